// Round 7
// baseline (163.515 us; speedup 1.0000x reference)
//
#include <hip/hip_runtime.h>
#include <hip/hip_bf16.h>

#define N_NODES 20000
#define BATCH   4
#define F_DIM   256
#define O_DIM   256
#define E_EDGES 160000
#define M_ROWS  (BATCH * N_NODES)   // 80000
#define K_DIM   512                 // concat: X (slices 0-7) | Xagg (slices 8-15)
// A layout: [16 slices][80000 rows][32 feats] bf16; row m = n*4 + b.
// Slice s holds feats 32s..32s+31. Per-slice row = 64B, so one edge's 4 batch
// rows are 256B contiguous -> XCD-pinned gather footprint = 5.1MB (~L2 size).
#define SLICE_A   2560000          // elems per A slice (80000*32)
#define SLICE_W   8192             // elems per Wt slice (256*32)

typedef __bf16 bf16_t;
typedef bf16_t bf16x8 __attribute__((ext_vector_type(8)));
typedef float  f32x4  __attribute__((ext_vector_type(4)));

// ---------- K1: fused X->bf16 sliced convert + weight transpose + deg zero ----------
__global__ void __launch_bounds__(256) k_prep(const float* __restrict__ X,
                                              const float* __restrict__ W1,
                                              const float* __restrict__ W2,
                                              bf16_t* __restrict__ A,
                                              bf16_t* __restrict__ Wt,
                                              int* __restrict__ deg) {
    const int bid = blockIdx.x;
    const int tid = threadIdx.x;
    if (bid < 10000) {
        const int m = bid * 8 + (tid >> 5);      // m = n*4 + b
        const int n = m >> 2, b = m & 3;
        const int col = (tid & 31) * 8;          // feat octet
        const float* src = X + ((size_t)b * N_NODES + n) * F_DIM + col;
        const float4 v0 = *reinterpret_cast<const float4*>(src);
        const float4 v1 = *reinterpret_cast<const float4*>(src + 4);
        bf16x8 o = { (bf16_t)v0.x, (bf16_t)v0.y, (bf16_t)v0.z, (bf16_t)v0.w,
                     (bf16_t)v1.x, (bf16_t)v1.y, (bf16_t)v1.z, (bf16_t)v1.w };
        const int s = col >> 5;
        *reinterpret_cast<bf16x8*>(A + (size_t)s * SLICE_A + (size_t)m * 32 + (col & 31)) = o;
    } else if (bid < 10512) {
        const int k = bid - 10000;   // 0..511
        const float v = (k < F_DIM) ? W1[(size_t)k * O_DIM + tid]
                                    : W2[(size_t)(k - F_DIM) * O_DIM + tid];
        Wt[(size_t)(k >> 5) * SLICE_W + (size_t)tid * 32 + (k & 31)] = (bf16_t)v;
    } else {
        const int idx = (bid - 10512) * 256 + tid;
        if (idx < N_NODES) deg[idx] = 0;
    }
}

// ---------- CSR build ----------
__global__ void k_deg(const int* __restrict__ rows, int* __restrict__ deg) {
    int e = blockIdx.x * 256 + threadIdx.x;
    atomicAdd(&deg[rows[e]], 1);
}

__global__ void __launch_bounds__(1024) k_scan(const int* __restrict__ deg,
                                               int* __restrict__ offsets,
                                               int* __restrict__ cursor) {
    __shared__ int wsum[16];
    const int t = threadIdx.x;          // 0..1023
    const int lane = t & 63, wv = t >> 6;
    const int CH = 20;
    int b = t * CH; if (b > N_NODES) b = N_NODES;
    int e = b + CH; if (e > N_NODES) e = N_NODES;
    int s = 0;
    for (int i = b; i < e; ++i) s += deg[i];
    int ps = s;
#pragma unroll
    for (int off = 1; off < 64; off <<= 1) {
        int o = __shfl_up(ps, off);
        if (lane >= off) ps += o;
    }
    if (lane == 63) wsum[wv] = ps;
    __syncthreads();
    if (t == 0) {
        int run = 0;
#pragma unroll
        for (int j = 0; j < 16; ++j) { int v = wsum[j]; wsum[j] = run; run += v; }
        offsets[N_NODES] = run;         // == E
    }
    __syncthreads();
    int run = wsum[wv] + (ps - s);
    for (int i = b; i < e; ++i) {
        offsets[i] = run; cursor[i] = run;
        run += deg[i];
    }
}

__global__ void k_scatter(const int* __restrict__ rows, const int* __restrict__ cols,
                          const float* __restrict__ vals, int* __restrict__ cursor,
                          int* __restrict__ ccol, float* __restrict__ cval) {
    int e = blockIdx.x * 256 + threadIdx.x;
    int r = rows[e];
    int p = atomicAdd(&cursor[r], 1);
    ccol[p] = cols[e];
    cval[p] = vals[e];
}

// ---------- SpMM, feature-sliced + XCD-pinned ----------
// Block -> slice x = blockIdx&7 (XCD-pinned via round-robin dispatch).
// Wave handles one node; 4 groups of 16 lanes each take every-4th edge;
// lane sub covers (batch sub>>2, feat-octet sub&3): addr = c*128 + sub*8.
// Cross-group reduce via shfl_xor(32,16), group 0 writes 256B/node.
__global__ void __launch_bounds__(256) k_spmm(const bf16_t* __restrict__ A,
                                              const int* __restrict__ offsets,
                                              const int* __restrict__ ccol,
                                              const float* __restrict__ cval,
                                              bf16_t* __restrict__ Aout) {
    const int x = blockIdx.x & 7;
    const int chunk = blockIdx.x >> 3;             // 0..1249
    const int w = threadIdx.x >> 6, lane = threadIdx.x & 63;
    const int g = lane >> 4, sub = lane & 15;
    const bf16_t* Xs = A + (size_t)x * SLICE_A + sub * 8;
    bf16_t* Ys = (bf16_t*)Aout + (size_t)(8 + x) * SLICE_A + sub * 8;
#pragma unroll
    for (int it = 0; it < 4; ++it) {
        const int n = chunk * 16 + it * 4 + w;
        const int beg = offsets[n], end = offsets[n + 1];
        float acc[8] = {0.f,0.f,0.f,0.f,0.f,0.f,0.f,0.f};
        for (int i = beg + g; i < end; i += 4) {
            const int c = ccol[i];
            const float v = cval[i];
            bf16x8 xv = *reinterpret_cast<const bf16x8*>(Xs + (size_t)c * 128);
#pragma unroll
            for (int j = 0; j < 8; ++j) acc[j] += v * (float)xv[j];
        }
#pragma unroll
        for (int j = 0; j < 8; ++j) {
            acc[j] += __shfl_xor(acc[j], 32);
            acc[j] += __shfl_xor(acc[j], 16);
        }
        if (g == 0) {
            bf16x8 o = { (bf16_t)acc[0], (bf16_t)acc[1], (bf16_t)acc[2], (bf16_t)acc[3],
                         (bf16_t)acc[4], (bf16_t)acc[5], (bf16_t)acc[6], (bf16_t)acc[7] };
            *reinterpret_cast<bf16x8*>(Ys + (size_t)n * 128) = o;
        }
    }
}

// ---------- GEMM: out[(m&3)*N + (m>>2), o] = sum_k A[m,k]*Wt[o,k] + bias[o] ----------
// Same pipeline/LDS/swizzle as round 5 (which dropped out of top-5); only the
// staging source addresses changed to the sliced layout.
#define GLOAD_LDS16(gptr, lptr)                                                  \
    __builtin_amdgcn_global_load_lds(                                            \
        (const __attribute__((address_space(1))) unsigned int*)(gptr),           \
        (__attribute__((address_space(3))) unsigned int*)(lptr), 16, 0, 0)

__global__ void __launch_bounds__(256, 2) k_gemm(const bf16_t* __restrict__ A,   // sliced
                                                 const bf16_t* __restrict__ Bt,  // sliced Wt
                                                 const float* __restrict__ bias,
                                                 float* __restrict__ out) {      // [B*N][256]
    __shared__ bf16_t As[2 * 128 * 64];   // 32 KB
    __shared__ bf16_t Bs[2 * 128 * 64];   // 32 KB

    const int b0 = blockIdx.x;
    const int xcd = b0 & 7, idx = b0 >> 3;
    const int serial = (xcd < 2 ? xcd * 157 : 314 + (xcd - 2) * 156) + idx;
    const int tile_m = (serial >> 1) * 128;
    const int tile_n = (serial & 1) * 128;

    const int tid = threadIdx.x;
    const int lane = tid & 63;
    const int w = tid >> 6;
    const int wm = (w >> 1) * 64;
    const int wn = (w & 1) * 64;

    f32x4 acc[4][4];
#pragma unroll
    for (int i = 0; i < 4; ++i)
#pragma unroll
        for (int j = 0; j < 4; ++j) acc[i][j] = (f32x4){0.f, 0.f, 0.f, 0.f};

    // K-step t covers slices {2t, 2t+1}. LDS[row][j] = source chunk jj = j^(row&7);
    // chunk jj -> slice 2t+(jj>>2), in-slice offset row*32 + (jj&3)*8.
    auto STAGE = [&](int buf, int t) {
#pragma unroll
        for (int r = 0; r < 4; ++r) {
            const int c = r * 256 + tid;           // 0..1023
            const int row = c >> 3;
            const int jj = (c & 7) ^ (row & 7);
            const int s = t * 2 + (jj >> 2);
            GLOAD_LDS16(A  + (size_t)s * SLICE_A + (size_t)(tile_m + row) * 32 + (jj & 3) * 8,
                        &As[buf * 8192 + c * 8]);
            GLOAD_LDS16(Bt + (size_t)s * SLICE_W + (size_t)(tile_n + row) * 32 + (jj & 3) * 8,
                        &Bs[buf * 8192 + c * 8]);
        }
    };
    auto COMPUTE = [&](int buf) {
        const bf16_t* a  = &As[buf * 8192];
        const bf16_t* bb = &Bs[buf * 8192];
#pragma unroll
        for (int ks = 0; ks < 2; ++ks) {
            const int ch = ((((ks << 2) | (lane >> 4)) ^ (lane & 7)) << 3);
            bf16x8 af[4];
#pragma unroll
            for (int i = 0; i < 4; ++i)
                af[i] = *reinterpret_cast<const bf16x8*>(a + (wm + i * 16 + (lane & 15)) * 64 + ch);
#pragma unroll
            for (int j = 0; j < 4; ++j) {
                bf16x8 bfr = *reinterpret_cast<const bf16x8*>(bb + (wn + j * 16 + (lane & 15)) * 64 + ch);
#pragma unroll
                for (int i = 0; i < 4; ++i)
                    acc[i][j] = __builtin_amdgcn_mfma_f32_16x16x32_bf16(af[i], bfr, acc[i][j], 0, 0, 0);
            }
        }
    };

    STAGE(0, 0);
    __syncthreads();
#pragma unroll
    for (int t = 0; t < 8; t += 2) {
        STAGE(1, t + 1);
        COMPUTE(0);
        __syncthreads();
        if (t + 2 < 8) STAGE(0, t + 2);
        COMPUTE(1);
        __syncthreads();
    }

#pragma unroll
    for (int j = 0; j < 4; ++j) {
        const int col = tile_n + wn + j * 16 + (lane & 15);
        const float bv = bias[col];
#pragma unroll
        for (int i = 0; i < 4; ++i) {
            const int m0 = tile_m + wm + i * 16 + ((lane >> 4) << 2);
#pragma unroll
            for (int r = 0; r < 4; ++r) {
                const int m = m0 + r;                       // m = n*4 + b
                const size_t orow = (size_t)(m & 3) * N_NODES + (m >> 2);
                out[orow * O_DIM + col] = acc[i][j][r] + bv;
            }
        }
    }
}

extern "C" void kernel_launch(void* const* d_in, const int* in_sizes, int n_in,
                              void* d_out, int out_size, void* d_ws, size_t ws_size,
                              hipStream_t stream) {
    const float* X    = (const float*)d_in[0];
    const int*   rows = (const int*)d_in[1];
    const int*   cols = (const int*)d_in[2];
    const float* vals = (const float*)d_in[3];
    const float* W1   = (const float*)d_in[4];
    const float* W2   = (const float*)d_in[5];
    const float* bias = (const float*)d_in[6];
    float* out = (float*)d_out;

    char* ws = (char*)d_ws;
    size_t off = 0;
    bf16_t* Abuf = (bf16_t*)(ws + off); off += (size_t)16 * SLICE_A * 2;     // 81,920,000 B
    bf16_t* Wt   = (bf16_t*)(ws + off); off += (size_t)16 * SLICE_W * 2;     // 262,144 B
    int* deg     = (int*)(ws + off);    off += (size_t)N_NODES * 4;
    int* offsets = (int*)(ws + off);    off += (size_t)(N_NODES + 1) * 4;
    int* cursor  = (int*)(ws + off);    off += (size_t)N_NODES * 4;
    off = (off + 15) & ~(size_t)15;
    int*   ccol  = (int*)(ws + off);    off += (size_t)E_EDGES * 4;
    float* cval  = (float*)(ws + off);  off += (size_t)E_EDGES * 4;

    k_prep<<<10591, 256, 0, stream>>>(X, W1, W2, Abuf, Wt, deg);
    k_deg<<<E_EDGES / 256, 256, 0, stream>>>(rows, deg);
    k_scan<<<1, 1024, 0, stream>>>(deg, offsets, cursor);
    k_scatter<<<E_EDGES / 256, 256, 0, stream>>>(rows, cols, vals, cursor, ccol, cval);
    k_spmm<<<10000, 256, 0, stream>>>(Abuf, offsets, ccol, cval, Abuf);
    k_gemm<<<(M_ROWS / 128) * (O_DIM / 128), 256, 0, stream>>>(Abuf, Wt, bias, out);
}

// Round 8
// 145.723 us; speedup vs baseline: 1.1221x; 1.1221x over previous
//
#include <hip/hip_runtime.h>
#include <hip/hip_bf16.h>

#define N_NODES 20000
#define BATCH   4
#define F_DIM   256
#define O_DIM   256
#define E_EDGES 160000
#define M_ROWS  (BATCH * N_NODES)   // 80000
#define K_DIM   512                 // concat: X (slices 0-7) | Xagg (slices 8-15)
// A layout: [16 slices][80000 rows][32 feats] bf16; row m = n*4 + b.
// Slice s holds feats 32s..32s+31. Per-slice row = 64B, so one edge's 4 batch
// rows are 256B contiguous -> XCD-pinned gather footprint = 5.1MB (~L2 size).
#define SLICE_A   2560000          // elems per A slice (80000*32)
#define SLICE_W   8192             // elems per Wt slice (256*32)

typedef __bf16 bf16_t;
typedef bf16_t bf16x8 __attribute__((ext_vector_type(8)));
typedef float  f32x4  __attribute__((ext_vector_type(4)));

// ---------- K1: fused X->bf16 sliced convert + weight transpose + deg zero ----------
__global__ void __launch_bounds__(256) k_prep(const float* __restrict__ X,
                                              const float* __restrict__ W1,
                                              const float* __restrict__ W2,
                                              bf16_t* __restrict__ A,
                                              bf16_t* __restrict__ Wt,
                                              int* __restrict__ deg) {
    const int bid = blockIdx.x;
    const int tid = threadIdx.x;
    if (bid < 10000) {
        const int m = bid * 8 + (tid >> 5);      // m = n*4 + b
        const int n = m >> 2, b = m & 3;
        const int col = (tid & 31) * 8;          // feat octet
        const float* src = X + ((size_t)b * N_NODES + n) * F_DIM + col;
        const float4 v0 = *reinterpret_cast<const float4*>(src);
        const float4 v1 = *reinterpret_cast<const float4*>(src + 4);
        bf16x8 o = { (bf16_t)v0.x, (bf16_t)v0.y, (bf16_t)v0.z, (bf16_t)v0.w,
                     (bf16_t)v1.x, (bf16_t)v1.y, (bf16_t)v1.z, (bf16_t)v1.w };
        const int s = col >> 5;
        *reinterpret_cast<bf16x8*>(A + (size_t)s * SLICE_A + (size_t)m * 32 + (col & 31)) = o;
    } else if (bid < 10512) {
        const int k = bid - 10000;   // 0..511
        const float v = (k < F_DIM) ? W1[(size_t)k * O_DIM + tid]
                                    : W2[(size_t)(k - F_DIM) * O_DIM + tid];
        Wt[(size_t)(k >> 5) * SLICE_W + (size_t)tid * 32 + (k & 31)] = (bf16_t)v;
    } else {
        const int idx = (bid - 10512) * 256 + tid;
        if (idx < N_NODES) deg[idx] = 0;
    }
}

// ---------- CSR build ----------
__global__ void k_deg(const int* __restrict__ rows, int* __restrict__ deg) {
    int e = blockIdx.x * 256 + threadIdx.x;
    atomicAdd(&deg[rows[e]], 1);
}

__global__ void __launch_bounds__(1024) k_scan(const int* __restrict__ deg,
                                               int* __restrict__ offsets,
                                               int* __restrict__ cursor) {
    __shared__ int wsum[16];
    const int t = threadIdx.x;          // 0..1023
    const int lane = t & 63, wv = t >> 6;
    const int CH = 20;
    int b = t * CH; if (b > N_NODES) b = N_NODES;
    int e = b + CH; if (e > N_NODES) e = N_NODES;
    int s = 0;
    for (int i = b; i < e; ++i) s += deg[i];
    int ps = s;
#pragma unroll
    for (int off = 1; off < 64; off <<= 1) {
        int o = __shfl_up(ps, off);
        if (lane >= off) ps += o;
    }
    if (lane == 63) wsum[wv] = ps;
    __syncthreads();
    if (t == 0) {
        int run = 0;
#pragma unroll
        for (int j = 0; j < 16; ++j) { int v = wsum[j]; wsum[j] = run; run += v; }
        offsets[N_NODES] = run;         // == E
    }
    __syncthreads();
    int run = wsum[wv] + (ps - s);
    for (int i = b; i < e; ++i) {
        offsets[i] = run; cursor[i] = run;
        run += deg[i];
    }
}

__global__ void k_scatter(const int* __restrict__ rows, const int* __restrict__ cols,
                          const float* __restrict__ vals, int* __restrict__ cursor,
                          int* __restrict__ ccol, float* __restrict__ cval) {
    int e = blockIdx.x * 256 + threadIdx.x;
    int r = rows[e];
    int p = atomicAdd(&cursor[r], 1);
    ccol[p] = cols[e];
    cval[p] = vals[e];
}

// ---------- SpMM, feature-sliced + XCD-pinned, group-per-node (join-free) ----------
// Block = slice x (blockIdx&7, XCD-pinned) x 16 nodes. Group g (16 lanes) owns
// node chunk*16+g entirely: edge loop unroll-4 -> 4 independent gathers in
// flight; no shfl reduce, no joins (r7's per-it join killed MLP: 56us at 25%
// HBM / 40% VALU). Group writes its 256B result once at the end.
__global__ void __launch_bounds__(256) k_spmm(const bf16_t* __restrict__ A,
                                              const int* __restrict__ offsets,
                                              const int* __restrict__ ccol,
                                              const float* __restrict__ cval,
                                              bf16_t* __restrict__ Aout) {
    const int x = blockIdx.x & 7;
    const int chunk = blockIdx.x >> 3;             // 0..1249
    const int g = threadIdx.x >> 4;                // 0..15: node group
    const int sub = threadIdx.x & 15;              // (batch sub>>2, feat-octet sub&3)
    const int n = chunk * 16 + g;
    const bf16_t* Xs = A + (size_t)x * SLICE_A + sub * 8;
    const int beg = offsets[n], end = offsets[n + 1];
    float acc[8] = {0.f,0.f,0.f,0.f,0.f,0.f,0.f,0.f};
    int i = beg;
    for (; i + 4 <= end; i += 4) {
        const int   c0 = ccol[i],   c1 = ccol[i+1], c2 = ccol[i+2], c3 = ccol[i+3];
        const float v0 = cval[i],   v1 = cval[i+1], v2 = cval[i+2], v3 = cval[i+3];
        bf16x8 x0 = *reinterpret_cast<const bf16x8*>(Xs + (size_t)c0 * 128);
        bf16x8 x1 = *reinterpret_cast<const bf16x8*>(Xs + (size_t)c1 * 128);
        bf16x8 x2 = *reinterpret_cast<const bf16x8*>(Xs + (size_t)c2 * 128);
        bf16x8 x3 = *reinterpret_cast<const bf16x8*>(Xs + (size_t)c3 * 128);
#pragma unroll
        for (int j = 0; j < 8; ++j)
            acc[j] += v0 * (float)x0[j] + v1 * (float)x1[j]
                    + v2 * (float)x2[j] + v3 * (float)x3[j];
    }
    for (; i < end; ++i) {
        const int c0 = ccol[i];
        const float v0 = cval[i];
        bf16x8 x0 = *reinterpret_cast<const bf16x8*>(Xs + (size_t)c0 * 128);
#pragma unroll
        for (int j = 0; j < 8; ++j) acc[j] += v0 * (float)x0[j];
    }
    bf16x8 o = { (bf16_t)acc[0], (bf16_t)acc[1], (bf16_t)acc[2], (bf16_t)acc[3],
                 (bf16_t)acc[4], (bf16_t)acc[5], (bf16_t)acc[6], (bf16_t)acc[7] };
    *reinterpret_cast<bf16x8*>(
        Aout + (size_t)(8 + x) * SLICE_A + (size_t)n * 128 + sub * 8) = o;
}

// ---------- GEMM: out[(m&3)*N + (m>>2), o] = sum_k A[m,k]*Wt[o,k] + bias[o] ----------
#define GLOAD_LDS16(gptr, lptr)                                                  \
    __builtin_amdgcn_global_load_lds(                                            \
        (const __attribute__((address_space(1))) unsigned int*)(gptr),           \
        (__attribute__((address_space(3))) unsigned int*)(lptr), 16, 0, 0)

__global__ void __launch_bounds__(256, 2) k_gemm(const bf16_t* __restrict__ A,   // sliced
                                                 const bf16_t* __restrict__ Bt,  // sliced Wt
                                                 const float* __restrict__ bias,
                                                 float* __restrict__ out) {      // [B*N][256]
    __shared__ bf16_t As[2 * 128 * 64];   // 32 KB
    __shared__ bf16_t Bs[2 * 128 * 64];   // 32 KB

    const int b0 = blockIdx.x;
    const int xcd = b0 & 7, idx = b0 >> 3;
    const int serial = (xcd < 2 ? xcd * 157 : 314 + (xcd - 2) * 156) + idx;
    const int tile_m = (serial >> 1) * 128;
    const int tile_n = (serial & 1) * 128;

    const int tid = threadIdx.x;
    const int lane = tid & 63;
    const int w = tid >> 6;
    const int wm = (w >> 1) * 64;
    const int wn = (w & 1) * 64;

    f32x4 acc[4][4];
#pragma unroll
    for (int i = 0; i < 4; ++i)
#pragma unroll
        for (int j = 0; j < 4; ++j) acc[i][j] = (f32x4){0.f, 0.f, 0.f, 0.f};

    // K-step t covers slices {2t, 2t+1}. LDS[row][j] = source chunk jj = j^(row&7);
    // chunk jj -> slice 2t+(jj>>2), in-slice offset row*32 + (jj&3)*8.
    auto STAGE = [&](int buf, int t) {
#pragma unroll
        for (int r = 0; r < 4; ++r) {
            const int c = r * 256 + tid;           // 0..1023
            const int row = c >> 3;
            const int jj = (c & 7) ^ (row & 7);
            const int s = t * 2 + (jj >> 2);
            GLOAD_LDS16(A  + (size_t)s * SLICE_A + (size_t)(tile_m + row) * 32 + (jj & 3) * 8,
                        &As[buf * 8192 + c * 8]);
            GLOAD_LDS16(Bt + (size_t)s * SLICE_W + (size_t)(tile_n + row) * 32 + (jj & 3) * 8,
                        &Bs[buf * 8192 + c * 8]);
        }
    };
    auto COMPUTE = [&](int buf) {
        const bf16_t* a  = &As[buf * 8192];
        const bf16_t* bb = &Bs[buf * 8192];
#pragma unroll
        for (int ks = 0; ks < 2; ++ks) {
            const int ch = ((((ks << 2) | (lane >> 4)) ^ (lane & 7)) << 3);
            bf16x8 af[4];
#pragma unroll
            for (int i = 0; i < 4; ++i)
                af[i] = *reinterpret_cast<const bf16x8*>(a + (wm + i * 16 + (lane & 15)) * 64 + ch);
#pragma unroll
            for (int j = 0; j < 4; ++j) {
                bf16x8 bfr = *reinterpret_cast<const bf16x8*>(bb + (wn + j * 16 + (lane & 15)) * 64 + ch);
#pragma unroll
                for (int i = 0; i < 4; ++i)
                    acc[i][j] = __builtin_amdgcn_mfma_f32_16x16x32_bf16(af[i], bfr, acc[i][j], 0, 0, 0);
            }
        }
    };

    STAGE(0, 0);
    __syncthreads();
#pragma unroll
    for (int t = 0; t < 8; t += 2) {
        STAGE(1, t + 1);
        COMPUTE(0);
        __syncthreads();
        if (t + 2 < 8) STAGE(0, t + 2);
        COMPUTE(1);
        __syncthreads();
    }

#pragma unroll
    for (int j = 0; j < 4; ++j) {
        const int col = tile_n + wn + j * 16 + (lane & 15);
        const float bv = bias[col];
#pragma unroll
        for (int i = 0; i < 4; ++i) {
            const int m0 = tile_m + wm + i * 16 + ((lane >> 4) << 2);
#pragma unroll
            for (int r = 0; r < 4; ++r) {
                const int m = m0 + r;                       // m = n*4 + b
                const size_t orow = (size_t)(m & 3) * N_NODES + (m >> 2);
                out[orow * O_DIM + col] = acc[i][j][r] + bv;
            }
        }
    }
}

extern "C" void kernel_launch(void* const* d_in, const int* in_sizes, int n_in,
                              void* d_out, int out_size, void* d_ws, size_t ws_size,
                              hipStream_t stream) {
    const float* X    = (const float*)d_in[0];
    const int*   rows = (const int*)d_in[1];
    const int*   cols = (const int*)d_in[2];
    const float* vals = (const float*)d_in[3];
    const float* W1   = (const float*)d_in[4];
    const float* W2   = (const float*)d_in[5];
    const float* bias = (const float*)d_in[6];
    float* out = (float*)d_out;

    char* ws = (char*)d_ws;
    size_t off = 0;
    bf16_t* Abuf = (bf16_t*)(ws + off); off += (size_t)16 * SLICE_A * 2;     // 81,920,000 B
    bf16_t* Wt   = (bf16_t*)(ws + off); off += (size_t)16 * SLICE_W * 2;     // 262,144 B
    int* deg     = (int*)(ws + off);    off += (size_t)N_NODES * 4;
    int* offsets = (int*)(ws + off);    off += (size_t)(N_NODES + 1) * 4;
    int* cursor  = (int*)(ws + off);    off += (size_t)N_NODES * 4;
    off = (off + 15) & ~(size_t)15;
    int*   ccol  = (int*)(ws + off);    off += (size_t)E_EDGES * 4;
    float* cval  = (float*)(ws + off);  off += (size_t)E_EDGES * 4;

    k_prep<<<10591, 256, 0, stream>>>(X, W1, W2, Abuf, Wt, deg);
    k_deg<<<E_EDGES / 256, 256, 0, stream>>>(rows, deg);
    k_scan<<<1, 1024, 0, stream>>>(deg, offsets, cursor);
    k_scatter<<<E_EDGES / 256, 256, 0, stream>>>(rows, cols, vals, cursor, ccol, cval);
    k_spmm<<<10000, 256, 0, stream>>>(Abuf, offsets, ccol, cval, Abuf);
    k_gemm<<<(M_ROWS / 128) * (O_DIM / 128), 256, 0, stream>>>(Abuf, Wt, bias, out);
}